// Round 3
// baseline (1300.100 us; speedup 1.0000x reference)
//
#include <hip/hip_runtime.h>
#include <hip/hip_bf16.h>

// Problem constants (from reference)
#define N_NODES 100000
#define N_EDGES 1600000
#define N_RELS  8
#define IN_F    64
#define HID_F   64
#define OUT_F   32
#define NSEG    (N_NODES * N_RELS)      // 800000 (node, rel) segments
#define SCAN_EPB 1024                   // elements per scan block (256 thr x 4)
#define SCAN_NB  ((NSEG + SCAN_EPB - 1) / SCAN_EPB)  // 782

typedef __attribute__((ext_vector_type(8))) short short8;   // 8 bf16 = 4 VGPRs
typedef __attribute__((ext_vector_type(4))) float f32x4;
typedef __attribute__((ext_vector_type(16))) int int16v;    // 16 SGPRs

__device__ __forceinline__ float b2f(unsigned short u) {
    return __uint_as_float(((unsigned)u) << 16);
}
__device__ __forceinline__ unsigned short f2b(float f) {
    unsigned u = __float_as_uint(f);
    u += 0x7FFFu + ((u >> 16) & 1u);      // RNE
    return (unsigned short)(u >> 16);
}
// Wave-uniform pointer, provably uniform for "s" asm constraints.
__device__ __forceinline__ unsigned long long uni_ptr(const void* p) {
    unsigned long long up = (unsigned long long)p;
    unsigned lo = __builtin_amdgcn_readfirstlane((unsigned)up);
    unsigned hi = __builtin_amdgcn_readfirstlane((unsigned)(up >> 32));
    return ((unsigned long long)hi << 32) | lo;
}

#define PREP_W1 (576 * 64)
#define PREP_W2 (576 * 32)
#define PREP_CVT (N_NODES * 64 / 4)
#define PREP_TOT (PREP_W1 + PREP_W2 + PREP_CVT)

// ---------------------------------------------------------------------------
// 1) Histogram + rank (atomic-free scatter later), with prep work fused in.
// ---------------------------------------------------------------------------
__global__ void k_hist(const int* __restrict__ dst, const int* __restrict__ et,
                       int* __restrict__ cnt, int* __restrict__ rank,
                       const float* __restrict__ W1, const float* __restrict__ root1,
                       const float* __restrict__ W2, const float* __restrict__ root2,
                       const float* __restrict__ x,
                       ushort* __restrict__ Wt1b, ushort* __restrict__ Wt2b,
                       ushort* __restrict__ xb) {
    const int e = blockIdx.x * 256 + threadIdx.x;
    const int gsz = gridDim.x * 256;
    // prep (independent; overlaps atomic latency)
    for (int j = e; j < PREP_TOT; j += gsz) {
        if (j < PREP_W1) {
            int o = j / 576, k = j - o * 576;
            float v = (k < 512) ? W1[k * 64 + o] : root1[(k - 512) * 64 + o];
            Wt1b[j] = f2b(v);
        } else if (j < PREP_W1 + PREP_W2) {
            int j2 = j - PREP_W1;
            int o = j2 / 576, k = j2 - o * 576;
            float v = (k < 512) ? W2[k * 32 + o] : root2[(k - 512) * 32 + o];
            Wt2b[j2] = f2b(v);
        } else {
            int j2 = j - PREP_W1 - PREP_W2;
            float4 v = *(const float4*)(x + (size_t)j2 * 4);
            ushort4 u;
            u.x = f2b(v.x); u.y = f2b(v.y); u.z = f2b(v.z); u.w = f2b(v.w);
            *(ushort4*)(xb + (size_t)j2 * 4) = u;
        }
    }
    if (e < N_EDGES) {
        int seg = dst[e] * N_RELS + et[e];
        rank[e] = atomicAdd(&cnt[seg], 1);
    }
}

// ---------------------------------------------------------------------------
// 2a) Scan pass A: per-block sums (1024 elems / block, 256 threads x 4)
// ---------------------------------------------------------------------------
__global__ void k_scanA(const int* __restrict__ cnt, int* __restrict__ bsums) {
    __shared__ int red[256];
    int t = threadIdx.x;
    int base = blockIdx.x * SCAN_EPB + t * 4;
    int s = 0;
    #pragma unroll
    for (int j = 0; j < 4; ++j) {
        int idx = base + j;
        if (idx < NSEG) s += cnt[idx];
    }
    red[t] = s;
    __syncthreads();
    for (int st = 128; st > 0; st >>= 1) {
        if (t < st) red[t] += red[t + st];
        __syncthreads();
    }
    if (t == 0) bsums[blockIdx.x] = red[0];
}

// ---------------------------------------------------------------------------
// 2b) Scan pass C (scanB inlined)
// ---------------------------------------------------------------------------
__global__ void k_scanC(const int* __restrict__ cnt, const int* __restrict__ bsums,
                        int* __restrict__ offs) {
    __shared__ int red[256];
    __shared__ int ts[256];
    int t = threadIdx.x;

    int partial = 0;
    #pragma unroll
    for (int jj = 0; jj < 4; ++jj) {
        int j = t + jj * 256;
        if (j < SCAN_NB && j < (int)blockIdx.x) partial += bsums[j];
    }
    red[t] = partial;
    __syncthreads();
    for (int st = 128; st > 0; st >>= 1) {
        if (t < st) red[t] += red[t + st];
        __syncthreads();
    }
    const int base0 = red[0];

    int base = blockIdx.x * SCAN_EPB + t * 4;
    int v[4];
    int local = 0;
    #pragma unroll
    for (int j = 0; j < 4; ++j) {
        int idx = base + j;
        v[j] = (idx < NSEG) ? cnt[idx] : 0;
        local += v[j];
    }
    ts[t] = local;
    __syncthreads();
    for (int off = 1; off < 256; off <<= 1) {
        int x = (t >= off) ? ts[t - off] : 0;
        __syncthreads();
        ts[t] += x;
        __syncthreads();
    }
    int run = base0 + (ts[t] - local);
    #pragma unroll
    for (int j = 0; j < 4; ++j) {
        int idx = base + j;
        if (idx < NSEG) offs[idx] = run;
        run += v[j];
    }
}

// ---------------------------------------------------------------------------
// 3) Pure scatter: ssrc[offs[seg]+rank] = (src<<7) | ((dst&15)<<3) | rel
//    7 low bits = the LDS row index (node-nibble*8 + rel) used by k_layer.
// ---------------------------------------------------------------------------
__global__ void k_scat(const int* __restrict__ src, const int* __restrict__ dst,
                       const int* __restrict__ et, const int* __restrict__ offs,
                       const int* __restrict__ rank, int* __restrict__ ssrc) {
    int e = blockIdx.x * 256 + threadIdx.x;
    if (e < N_EDGES) {
        int r = et[e];
        int d = dst[e];
        int seg = d * N_RELS + r;
        ssrc[offs[seg] + rank[e]] = (src[e] << 7) | ((d & 15) << 3) | r;
    }
}

// ---------------------------------------------------------------------------
// 4) Fused layer — ds_add_f32 accumulation structure (R2/R3).
//    Block = 512 thr = 8 waves, 16 nodes.
//    Phase 1: ONE flat loop over the block's whole edge range (contiguous in
//    ssrc since it is sorted by (dst,rel)), split into 8 balanced per-wave
//    stripes. Edge metadata via s_load_dwordx16 (scalar cache, 64B-aligned,
//    base made provably uniform with readfirstlane -> SGPR-pair operand).
//    Per edge: ushort row gather (64 lanes), b2f shift, ds_add_f32 into the
//    (node,rel) fp32 LDS row. No readlanes, no rel-boundary flushes, no
//    per-node padding. fp32 atomic reorder ~1ulp — inside bf16 tolerance.
//    Phase 1.5: normalize (invT) + convert to bf16 MFMA tiles in-place
//    (read->regs->sync->write union overlay).
//    Phase 2: MFMA 16x16x32 bf16, 8 waves = NT n-tiles x S k-splits.
//    Phase 3: k-split partial C reduce via LDS, bias (+ReLU), store.
//    LDS: 32KB fp32 rows (union 18.7KB bf16 tiles) + pc 6KB + invT 0.5KB
//    = 39.4KB -> 4 blocks/CU if VGPR<=64.
// ---------------------------------------------------------------------------
template <int NOUT, bool RELU, typename OutT>
__global__ __launch_bounds__(512, 4) void k_layer(
        const ushort* __restrict__ xb, const int* __restrict__ offs,
        const int* __restrict__ cnt, const int* __restrict__ ssrc,
        const ushort* __restrict__ Wtb, const float* __restrict__ bias,
        OutT* __restrict__ out) {
    constexpr int NT = NOUT / 16;     // n-tiles
    constexpr int S  = 8 / NT;        // k-splits
    __shared__ __align__(16) union {
        float  a32[128][64];          // (node-nib*8+rel) fp32 raw sums, 32KB
        ushort a16[16][584];          // bf16 A tiles (+root @512), 18.7KB
    } U;
    __shared__ float invT[128];
    __shared__ f32x4 pc[6][64];       // k-split partials

    const int tid = threadIdx.x;
    const int w = tid >> 6;
    const int f = tid & 63;
    const int node0 = blockIdx.x * 16;

    // ---- phase-2 wave assignment; preload first B-frag early ----
    const int t = w % NT, q = w / NT;
    constexpr int cbase = 18 / S, crem = 18 % S;
    const int cs = q * cbase + (q < crem ? q : crem);
    const int ce = cs + cbase + (q < crem ? 1 : 0);
    const int n0 = t * 16;
    const ushort* bptr = Wtb + (n0 + (f & 15)) * 576 + ((f >> 4) * 8);
    short8 bcur = *(const short8*)(bptr + cs * 32);

    // ---- phase 0: zero fp32 rows, build inv table ----
    float* S32 = &U.a32[0][0];
    {
        f32x4 z = (f32x4){0.0f, 0.0f, 0.0f, 0.0f};
        #pragma unroll
        for (int k = 0; k < 4; ++k)
            *(f32x4*)(S32 + tid * 16 + k * 4) = z;
        if (tid < 128) {
            int c = cnt[node0 * 8 + tid];
            invT[tid] = 1.0f / (float)(c > 0 ? c : 1);
        }
    }
    const int start = offs[node0 * 8];
    const int end = (node0 + 16 >= N_NODES) ? N_EDGES : offs[(node0 + 16) * 8];
    __syncthreads();

    // ---- phase 1: balanced per-wave stripes over block edge range ----
    {
        const int tot = end - start;
        const int ebase = tot >> 3, erem = tot & 7;
        const int ms = start + w * ebase + (w < erem ? w : erem);
        const int me = ms + ebase + (w < erem ? 1 : 0);
        if (ms < me) {
            unsigned long long sp = uni_ptr(ssrc + (ms & ~15));
            for (int pos = ms & ~15; pos < me; pos += 16, sp += 64) {
                int16v g;
                asm volatile("s_load_dwordx16 %0, %1, 0x0\n\t"
                             "s_waitcnt lgkmcnt(0)"
                             : "=s"(g) : "s"(sp));
                if (pos >= ms && pos + 16 <= me) {        // uniform fast path
                    #pragma unroll
                    for (int j = 0; j < 16; ++j) {
                        int sk = g[j];
                        float xv = b2f(xb[(((unsigned)sk >> 7) << 6) + (unsigned)f]);
                        atomicAdd(&U.a32[sk & 127][f], xv);   // ds_add_f32
                    }
                } else {                                   // edge groups, guarded
                    #pragma unroll
                    for (int j = 0; j < 16; ++j) {
                        if (pos + j >= ms && pos + j < me) {
                            int sk = g[j];
                            float xv = b2f(xb[(((unsigned)sk >> 7) << 6) + (unsigned)f]);
                            atomicAdd(&U.a32[sk & 127][f], xv);
                        }
                    }
                }
            }
        }
    }
    __syncthreads();

    // ---- phase 1.5: normalize + bf16-convert, in-place via reg staging ----
    float rv[16];
    {
        const int row = tid >> 2;            // 0..127 (node-nib*8+rel)
        const int fb = (tid & 3) * 16;
        const float inv = invT[row];
        #pragma unroll
        for (int k = 0; k < 4; ++k) {
            f32x4 v = *(f32x4*)(S32 + row * 64 + fb + k * 4);
            rv[k * 4 + 0] = v.x * inv; rv[k * 4 + 1] = v.y * inv;
            rv[k * 4 + 2] = v.z * inv; rv[k * 4 + 3] = v.w * inv;
        }
    }
    __syncthreads();                          // all fp32 reads done
    {
        const int row = tid >> 2;
        const int nib = row >> 3, rel = row & 7;
        const int fb = (tid & 3) * 16;
        ushort* dp = &U.a16[nib][rel * 64 + fb];
        short8 o0, o1;
        #pragma unroll
        for (int k = 0; k < 8; ++k) o0[k] = (short)f2b(rv[k]);
        #pragma unroll
        for (int k = 0; k < 8; ++k) o1[k] = (short)f2b(rv[8 + k]);
        *(short8*)dp = o0;
        *(short8*)(dp + 8) = o1;
        // root rows: 2 bf16 per thread straight from input
        const int m = tid >> 5, f2 = (tid & 31) * 2;
        uint xr = *(const uint*)(xb + (size_t)(node0 + m) * 64 + f2);
        *(uint*)&U.a16[m][512 + f2] = xr;
    }
    __syncthreads();

    // ---- Phase 2: MFMA over this wave's chunks (software-pipelined B) ----
    f32x4 acc = (f32x4){0.0f, 0.0f, 0.0f, 0.0f};
    const ushort* aptr = &U.a16[f & 15][(f >> 4) * 8];
    for (int c = cs; c < ce; ++c) {
        short8 bnext = bcur;
        if (c + 1 < ce) bnext = *(const short8*)(bptr + (c + 1) * 32);
        short8 af = *(const short8*)(aptr + c * 32);
        acc = __builtin_amdgcn_mfma_f32_16x16x32_bf16(af, bcur, acc, 0, 0, 0);
        bcur = bnext;
    }

    // ---- Phase 3: reduce k-splits, bias (+ReLU), store ----
    if (q > 0) pc[w - NT][f] = acc;
    __syncthreads();
    if (q == 0) {
        #pragma unroll
        for (int j = 1; j < S; ++j) {
            f32x4 p = pc[t + NT * (j - 1)][f];
            acc.x += p.x; acc.y += p.y; acc.z += p.z; acc.w += p.w;
        }
        const int col = f & 15;
        const float bs = bias[n0 + col];
        const int mrow = (f >> 4) * 4;   // C/D: row=(lane>>4)*4+reg, col=lane&15
        #pragma unroll
        for (int i = 0; i < 4; ++i) {
            float v = acc[i] + bs;
            if (RELU) v = fmaxf(v, 0.0f);
            size_t oi = (size_t)(node0 + mrow + i) * NOUT + n0 + col;
            if constexpr (sizeof(OutT) == 2) out[oi] = (OutT)f2b(v);
            else                             out[oi] = (OutT)v;
        }
    }
}

// ---------------------------------------------------------------------------
// Launch: 7 dispatches (memset, hist+prep, scanA, scanC, scat, layer1, layer2)
// ---------------------------------------------------------------------------
extern "C" void kernel_launch(void* const* d_in, const int* in_sizes, int n_in,
                              void* d_out, int out_size, void* d_ws, size_t ws_size,
                              hipStream_t stream) {
    const float* x     = (const float*)d_in[0];
    const int*   ei    = (const int*)d_in[1];
    const int*   et    = (const int*)d_in[2];
    const float* W1    = (const float*)d_in[3];
    const float* root1 = (const float*)d_in[4];
    const float* b1    = (const float*)d_in[5];
    const float* W2    = (const float*)d_in[6];
    const float* root2 = (const float*)d_in[7];
    const float* b2    = (const float*)d_in[8];
    float* out = (float*)d_out;

    const int* src = ei;            // edge_index[0]
    const int* dst = ei + N_EDGES;  // edge_index[1]

    // Workspace layout (~38.5 MB):
    //   cnt 3.2M | offs 3.2M | bsums 4K | ssrc 6.4M | xb 12.8M |
    //   h1b 12.8M (rank overlaps its first 6.4M — dead before h1b written) |
    //   Wt1b 73.7K | Wt2b 36.9K
    char* ws = (char*)d_ws;
    int*    cnt   = (int*)(ws);
    int*    offs  = (int*)(ws + (size_t)NSEG * 4);
    int*    bsums = (int*)(ws + (size_t)NSEG * 8);
    int*    ssrc  = (int*)(ws + (size_t)NSEG * 8 + 4096);
    ushort* xb    = (ushort*)(ws + (size_t)NSEG * 8 + 4096 + (size_t)N_EDGES * 4);
    ushort* h1b   = (ushort*)((char*)xb + (size_t)N_NODES * 64 * 2);
    int*    rank  = (int*)h1b;   // overlap: rank dead after k_scat
    ushort* Wt1b  = (ushort*)((char*)h1b + (size_t)N_NODES * 64 * 2);
    ushort* Wt2b  = (ushort*)((char*)Wt1b + (size_t)PREP_W1 * 2);

    (void)hipMemsetAsync(cnt, 0, (size_t)NSEG * 4, stream);

    int eb = (N_EDGES + 255) / 256;
    k_hist<<<eb, 256, 0, stream>>>(dst, et, cnt, rank,
                                   W1, root1, W2, root2, x, Wt1b, Wt2b, xb);
    k_scanA<<<SCAN_NB, 256, 0, stream>>>(cnt, bsums);
    k_scanC<<<SCAN_NB, 256, 0, stream>>>(cnt, bsums, offs);
    k_scat<<<eb, 256, 0, stream>>>(src, dst, et, offs, rank, ssrc);

    // Layer 1: xb -> h1b (bf16, ReLU), NOUT=64
    k_layer<64, true, ushort><<<N_NODES / 16, 512, 0, stream>>>(
        xb, offs, cnt, ssrc, Wt1b, b1, h1b);
    // Layer 2: h1b -> out (fp32), NOUT=32
    k_layer<32, false, float><<<N_NODES / 16, 512, 0, stream>>>(
        h1b, offs, cnt, ssrc, Wt2b, b2, out);
}

// Round 4
// 358.688 us; speedup vs baseline: 3.6246x; 3.6246x over previous
//
#include <hip/hip_runtime.h>
#include <hip/hip_bf16.h>

// Problem constants (from reference)
#define N_NODES 100000
#define N_EDGES 1600000
#define N_RELS  8
#define IN_F    64
#define HID_F   64
#define OUT_F   32
#define NSEG    (N_NODES * N_RELS)      // 800000 (node, rel) segments
#define SCAN_EPB 1024                   // elements per scan block (256 thr x 4)
#define SCAN_NB  ((NSEG + SCAN_EPB - 1) / SCAN_EPB)  // 782

typedef __attribute__((ext_vector_type(8))) short short8;   // 8 bf16 = 4 VGPRs
typedef __attribute__((ext_vector_type(4))) float f32x4;

__device__ __forceinline__ float b2f(unsigned short u) {
    return __uint_as_float(((unsigned)u) << 16);
}
__device__ __forceinline__ unsigned short f2b(float f) {
    unsigned u = __float_as_uint(f);
    u += 0x7FFFu + ((u >> 16) & 1u);      // RNE
    return (unsigned short)(u >> 16);
}

#define PREP_W1 (576 * 64)
#define PREP_W2 (576 * 32)
#define PREP_CVT (N_NODES * 64 / 4)
#define PREP_TOT (PREP_W1 + PREP_W2 + PREP_CVT)

// ---------------------------------------------------------------------------
// 1) Histogram + rank (atomic-free scatter later), with prep work fused in.
// ---------------------------------------------------------------------------
__global__ void k_hist(const int* __restrict__ dst, const int* __restrict__ et,
                       int* __restrict__ cnt, int* __restrict__ rank,
                       const float* __restrict__ W1, const float* __restrict__ root1,
                       const float* __restrict__ W2, const float* __restrict__ root2,
                       const float* __restrict__ x,
                       ushort* __restrict__ Wt1b, ushort* __restrict__ Wt2b,
                       ushort* __restrict__ xb) {
    const int e = blockIdx.x * 256 + threadIdx.x;
    const int gsz = gridDim.x * 256;
    // prep (independent; overlaps atomic latency)
    for (int j = e; j < PREP_TOT; j += gsz) {
        if (j < PREP_W1) {
            int o = j / 576, k = j - o * 576;
            float v = (k < 512) ? W1[k * 64 + o] : root1[(k - 512) * 64 + o];
            Wt1b[j] = f2b(v);
        } else if (j < PREP_W1 + PREP_W2) {
            int j2 = j - PREP_W1;
            int o = j2 / 576, k = j2 - o * 576;
            float v = (k < 512) ? W2[k * 32 + o] : root2[(k - 512) * 32 + o];
            Wt2b[j2] = f2b(v);
        } else {
            int j2 = j - PREP_W1 - PREP_W2;
            float4 v = *(const float4*)(x + (size_t)j2 * 4);
            ushort4 u;
            u.x = f2b(v.x); u.y = f2b(v.y); u.z = f2b(v.z); u.w = f2b(v.w);
            *(ushort4*)(xb + (size_t)j2 * 4) = u;
        }
    }
    if (e < N_EDGES) {
        int seg = dst[e] * N_RELS + et[e];
        rank[e] = atomicAdd(&cnt[seg], 1);
    }
}

// ---------------------------------------------------------------------------
// 2a) Scan pass A: per-block sums (1024 elems / block, 256 threads x 4)
// ---------------------------------------------------------------------------
__global__ void k_scanA(const int* __restrict__ cnt, int* __restrict__ bsums) {
    __shared__ int red[256];
    int t = threadIdx.x;
    int base = blockIdx.x * SCAN_EPB + t * 4;
    int s = 0;
    #pragma unroll
    for (int j = 0; j < 4; ++j) {
        int idx = base + j;
        if (idx < NSEG) s += cnt[idx];
    }
    red[t] = s;
    __syncthreads();
    for (int st = 128; st > 0; st >>= 1) {
        if (t < st) red[t] += red[t + st];
        __syncthreads();
    }
    if (t == 0) bsums[blockIdx.x] = red[0];
}

// ---------------------------------------------------------------------------
// 2b) Scan pass C (scanB inlined)
// ---------------------------------------------------------------------------
__global__ void k_scanC(const int* __restrict__ cnt, const int* __restrict__ bsums,
                        int* __restrict__ offs) {
    __shared__ int red[256];
    __shared__ int ts[256];
    int t = threadIdx.x;

    int partial = 0;
    #pragma unroll
    for (int jj = 0; jj < 4; ++jj) {
        int j = t + jj * 256;
        if (j < SCAN_NB && j < (int)blockIdx.x) partial += bsums[j];
    }
    red[t] = partial;
    __syncthreads();
    for (int st = 128; st > 0; st >>= 1) {
        if (t < st) red[t] += red[t + st];
        __syncthreads();
    }
    const int base0 = red[0];

    int base = blockIdx.x * SCAN_EPB + t * 4;
    int v[4];
    int local = 0;
    #pragma unroll
    for (int j = 0; j < 4; ++j) {
        int idx = base + j;
        v[j] = (idx < NSEG) ? cnt[idx] : 0;
        local += v[j];
    }
    ts[t] = local;
    __syncthreads();
    for (int off = 1; off < 256; off <<= 1) {
        int x = (t >= off) ? ts[t - off] : 0;
        __syncthreads();
        ts[t] += x;
        __syncthreads();
    }
    int run = base0 + (ts[t] - local);
    #pragma unroll
    for (int j = 0; j < 4; ++j) {
        int idx = base + j;
        if (idx < NSEG) offs[idx] = run;
        run += v[j];
    }
}

// ---------------------------------------------------------------------------
// 3) Pure scatter: ssrc[offs[seg]+rank] = (src<<8) | ((dst&15)<<4) | rel
//    sk&15 = rel clean (bit3=0, pad sentinel 15 never collides);
//    sk>>8 = src row for the gather.
// ---------------------------------------------------------------------------
__global__ void k_scat(const int* __restrict__ src, const int* __restrict__ dst,
                       const int* __restrict__ et, const int* __restrict__ offs,
                       const int* __restrict__ rank, int* __restrict__ ssrc) {
    int e = blockIdx.x * 256 + threadIdx.x;
    if (e < N_EDGES) {
        int r = et[e];
        int d = dst[e];
        int seg = d * N_RELS + r;
        ssrc[offs[seg] + rank[e]] = (src[e] << 8) | ((d & 15) << 4) | r;
    }
}

// ---------------------------------------------------------------------------
// 4) Fused layer — R1 per-edge loop + raw-fp32 cheap flush (R4).
//    Block = 512 thr = 8 waves, 16 nodes. Wave w owns nodes {2w, 2w+1}.
//    Phase 1 (R1-identical per-edge path: readlane + gather + b2f + add +
//    uniform scalar rel-boundary check). FLUSH is now a single plain
//    ds_write_b32 of the raw fp32 running sum into the wave-owned
//    (node,rel) row — no division, no count readlane, no f2b (previously
//    ~14 ops x 800K flushes/layer ~= half of phase-1 issue).
//    Phase 1.5: normalize (invT built once per block) + bf16-convert, one
//    vectorized pass in-place via union overlay (R3-proven code). Math is
//    bit-identical to R1: same 1.0f/c division, same multiply.
//    Phase 2: MFMA 16x16x32 bf16, 8 waves = NT n-tiles x S k-splits.
//    Phase 3: k-split partial C reduce via LDS, bias (+ReLU), store.
//    LDS: 32KB fp32 rows (union 18.7KB bf16 tiles) + invT 0.5KB + pc 6KB
//    = 39.4KB -> 4 blocks/CU (VGPR ~36).
//    R3 lesson: NO LDS atomics in the edge path, NO smem loads whose
//    lgkmcnt(0) wait drains DS ops at per-edge density.
// ---------------------------------------------------------------------------
template <int NOUT, bool RELU, typename OutT>
__global__ __launch_bounds__(512, 4) void k_layer(
        const ushort* __restrict__ xb, const int* __restrict__ offs,
        const int* __restrict__ cnt, const int* __restrict__ ssrc,
        const ushort* __restrict__ Wtb, const float* __restrict__ bias,
        OutT* __restrict__ out) {
    constexpr int NT = NOUT / 16;     // n-tiles
    constexpr int S  = 8 / NT;        // k-splits
    __shared__ __align__(16) union {
        float  a32[128][64];          // (node-nib*8+rel) fp32 raw sums, 32KB
        ushort a16[16][584];          // bf16 A tiles (+root @512), 18.7KB
    } U;
    __shared__ float invT[128];
    __shared__ f32x4 pc[6][64];       // k-split partials

    const int tid = threadIdx.x;
    const int w = tid >> 6;
    const int f = tid & 63;
    const int node0 = blockIdx.x * 16;

    // ---- phase-2 wave assignment; preload first B-frag early ----
    const int t = w % NT, q = w / NT;
    constexpr int cbase = 18 / S, crem = 18 % S;
    const int cs = q * cbase + (q < crem ? q : crem);
    const int ce = cs + cbase + (q < crem ? 1 : 0);
    const int n0 = t * 16;
    const ushort* bptr = Wtb + (n0 + (f & 15)) * 576 + ((f >> 4) * 8);
    short8 bcur = *(const short8*)(bptr + cs * 32);

    // ---- phase 0: zero fp32 rows, build inv table ----
    float* S32 = &U.a32[0][0];
    {
        f32x4 z = (f32x4){0.0f, 0.0f, 0.0f, 0.0f};
        #pragma unroll
        for (int k = 0; k < 4; ++k)
            *(f32x4*)(S32 + tid * 16 + k * 4) = z;
        if (tid < 128) {
            int c = cnt[node0 * 8 + tid];
            invT[tid] = 1.0f / (float)(c > 0 ? c : 1);
        }
    }

    // ---- phase-1 metadata: lanes 0..15 -> offs/cnt for both nodes' 8 rels --
    int ov = 0, cv = 0;
    if (f < 16) {
        ov = offs[(node0 + w * 2) * N_RELS + f];
        cv = cnt [(node0 + w * 2) * N_RELS + f];
    }
    __syncthreads();                          // zeroing done before flushes

    for (int nd = 0; nd < 2; ++nd) {
        const int m = w * 2 + nd;
        const int s0 = __builtin_amdgcn_readlane(ov, nd * 8);
        const int ct = __builtin_amdgcn_readlane(ov, nd * 8 + 7)
                     + __builtin_amdgcn_readlane(cv, nd * 8 + 7) - s0;

        float running = 0.0f;
        int prl = 15;                         // "pad" rel: never flushed

        for (int cb = 0; cb < ct; cb += 64) {
            int n = ct - cb;
            if (n > 64) n = 64;
            int pk = 15;                      // pad: rel=15, src=0
            if (f < n) pk = ssrc[s0 + cb + f];
            for (int e = 0; e < n; e += 16) {
                int pv[16];
                float xv[16];
                #pragma unroll
                for (int i = 0; i < 16; ++i)
                    pv[i] = __builtin_amdgcn_readlane(pk, e + i);   // SGPR
                #pragma unroll
                for (int i = 0; i < 16; ++i)
                    xv[i] = b2f(xb[(size_t)((unsigned)pv[i] >> 8) * 64 + f]);
                #pragma unroll
                for (int i = 0; i < 16; ++i) {
                    const int rl = pv[i] & 15;            // rel, non-decreasing
                    if (rl != prl) {                      // uniform scalar branch
                        if (prl < 8)                      // cheap raw-sum flush
                            U.a32[(m << 3) + prl][f] = running;
                        running = 0.0f;
                        prl = rl;
                    }
                    running += xv[i];
                }
            }
        }
        if (prl < 8)                          // final flush
            U.a32[(m << 3) + prl][f] = running;
    }
    __syncthreads();

    // ---- phase 1.5: normalize + bf16-convert, in-place via reg staging ----
    float rv[16];
    {
        const int row = tid >> 2;            // 0..127 (node-nib*8+rel)
        const int fb = (tid & 3) * 16;
        const float inv = invT[row];
        #pragma unroll
        for (int k = 0; k < 4; ++k) {
            f32x4 v = *(f32x4*)(S32 + row * 64 + fb + k * 4);
            rv[k * 4 + 0] = v.x * inv; rv[k * 4 + 1] = v.y * inv;
            rv[k * 4 + 2] = v.z * inv; rv[k * 4 + 3] = v.w * inv;
        }
    }
    __syncthreads();                          // all fp32 reads done
    {
        const int row = tid >> 2;
        const int nib = row >> 3, rel = row & 7;
        const int fb = (tid & 3) * 16;
        ushort* dp = &U.a16[nib][rel * 64 + fb];
        short8 o0, o1;
        #pragma unroll
        for (int k = 0; k < 8; ++k) o0[k] = (short)f2b(rv[k]);
        #pragma unroll
        for (int k = 0; k < 8; ++k) o1[k] = (short)f2b(rv[8 + k]);
        *(short8*)dp = o0;
        *(short8*)(dp + 8) = o1;
        // root rows: 2 bf16 per thread straight from input
        const int m = tid >> 5, f2 = (tid & 31) * 2;
        uint xr = *(const uint*)(xb + (size_t)(node0 + m) * 64 + f2);
        *(uint*)&U.a16[m][512 + f2] = xr;
    }
    __syncthreads();

    // ---- Phase 2: MFMA over this wave's chunks (software-pipelined B) ----
    f32x4 acc = (f32x4){0.0f, 0.0f, 0.0f, 0.0f};
    const ushort* aptr = &U.a16[f & 15][(f >> 4) * 8];
    for (int c = cs; c < ce; ++c) {
        short8 bnext = bcur;
        if (c + 1 < ce) bnext = *(const short8*)(bptr + (c + 1) * 32);
        short8 af = *(const short8*)(aptr + c * 32);
        acc = __builtin_amdgcn_mfma_f32_16x16x32_bf16(af, bcur, acc, 0, 0, 0);
        bcur = bnext;
    }

    // ---- Phase 3: reduce k-splits, bias (+ReLU), store ----
    if (q > 0) pc[w - NT][f] = acc;
    __syncthreads();
    if (q == 0) {
        #pragma unroll
        for (int j = 1; j < S; ++j) {
            f32x4 p = pc[t + NT * (j - 1)][f];
            acc.x += p.x; acc.y += p.y; acc.z += p.z; acc.w += p.w;
        }
        const int col = f & 15;
        const float bs = bias[n0 + col];
        const int mrow = (f >> 4) * 4;   // C/D: row=(lane>>4)*4+reg, col=lane&15
        #pragma unroll
        for (int i = 0; i < 4; ++i) {
            float v = acc[i] + bs;
            if (RELU) v = fmaxf(v, 0.0f);
            size_t oi = (size_t)(node0 + mrow + i) * NOUT + n0 + col;
            if constexpr (sizeof(OutT) == 2) out[oi] = (OutT)f2b(v);
            else                             out[oi] = (OutT)v;
        }
    }
}

// ---------------------------------------------------------------------------
// Launch: 7 dispatches (memset, hist+prep, scanA, scanC, scat, layer1, layer2)
// ---------------------------------------------------------------------------
extern "C" void kernel_launch(void* const* d_in, const int* in_sizes, int n_in,
                              void* d_out, int out_size, void* d_ws, size_t ws_size,
                              hipStream_t stream) {
    const float* x     = (const float*)d_in[0];
    const int*   ei    = (const int*)d_in[1];
    const int*   et    = (const int*)d_in[2];
    const float* W1    = (const float*)d_in[3];
    const float* root1 = (const float*)d_in[4];
    const float* b1    = (const float*)d_in[5];
    const float* W2    = (const float*)d_in[6];
    const float* root2 = (const float*)d_in[7];
    const float* b2    = (const float*)d_in[8];
    float* out = (float*)d_out;

    const int* src = ei;            // edge_index[0]
    const int* dst = ei + N_EDGES;  // edge_index[1]

    // Workspace layout (~38.5 MB):
    //   cnt 3.2M | offs 3.2M | bsums 4K | ssrc 6.4M | xb 12.8M |
    //   h1b 12.8M (rank overlaps its first 6.4M — dead before h1b written) |
    //   Wt1b 73.7K | Wt2b 36.9K
    char* ws = (char*)d_ws;
    int*    cnt   = (int*)(ws);
    int*    offs  = (int*)(ws + (size_t)NSEG * 4);
    int*    bsums = (int*)(ws + (size_t)NSEG * 8);
    int*    ssrc  = (int*)(ws + (size_t)NSEG * 8 + 4096);
    ushort* xb    = (ushort*)(ws + (size_t)NSEG * 8 + 4096 + (size_t)N_EDGES * 4);
    ushort* h1b   = (ushort*)((char*)xb + (size_t)N_NODES * 64 * 2);
    int*    rank  = (int*)h1b;   // overlap: rank dead after k_scat
    ushort* Wt1b  = (ushort*)((char*)h1b + (size_t)N_NODES * 64 * 2);
    ushort* Wt2b  = (ushort*)((char*)Wt1b + (size_t)PREP_W1 * 2);

    (void)hipMemsetAsync(cnt, 0, (size_t)NSEG * 4, stream);

    int eb = (N_EDGES + 255) / 256;
    k_hist<<<eb, 256, 0, stream>>>(dst, et, cnt, rank,
                                   W1, root1, W2, root2, x, Wt1b, Wt2b, xb);
    k_scanA<<<SCAN_NB, 256, 0, stream>>>(cnt, bsums);
    k_scanC<<<SCAN_NB, 256, 0, stream>>>(cnt, bsums, offs);
    k_scat<<<eb, 256, 0, stream>>>(src, dst, et, offs, rank, ssrc);

    // Layer 1: xb -> h1b (bf16, ReLU), NOUT=64
    k_layer<64, true, ushort><<<N_NODES / 16, 512, 0, stream>>>(
        xb, offs, cnt, ssrc, Wt1b, b1, h1b);
    // Layer 2: h1b -> out (fp32), NOUT=32
    k_layer<32, false, float><<<N_NODES / 16, 512, 0, stream>>>(
        h1b, offs, cnt, ssrc, Wt2b, b2, out);
}